// Round 1
// 247.785 us; speedup vs baseline: 1.0183x; 1.0183x over previous
//
#include <hip/hip_runtime.h>
#include <stdint.h>

#define Tdim 128
#define Zdim 100
#define Sdim 6
#define Hdim 64
#define ZB   3200           // Z*B
#define F1   512
#define F2   128
#define Mrows (ZB * Tdim)   // 409600

typedef _Float16 f16x8 __attribute__((ext_vector_type(8)));
typedef _Float16 f16x4 __attribute__((ext_vector_type(4)));
typedef float f32x4 __attribute__((ext_vector_type(4)));
typedef uint32_t u32x4 __attribute__((ext_vector_type(4)));

__device__ __forceinline__ float sigmoidf_fast(float x) {
  return 1.f / (1.f + __expf(-x));
}
__device__ __forceinline__ float tanhf_fast(float x) {
  return 1.f - 2.f / (__expf(2.f * x) + 1.f);
}

// ---------------------------------------------------------------- prep
// Wf[192][96] fp16: [W_hh | W_ih | 0] per gate (K=96 fused), for the GRU.
// w1p frag-linear: [kt][ntl][kfrag][lane][8].  32768 f16.
// w2p frag-linear: [kt][nt][lane][8].          65536 f16.
__global__ __launch_bounds__(256) void prep_kernel(
    const float* __restrict__ W_ih, const float* __restrict__ W_hh,
    const float* __restrict__ w1, const float* __restrict__ w2,
    _Float16* __restrict__ Wf, _Float16* __restrict__ w1p,
    _Float16* __restrict__ w2p) {
  int i = blockIdx.x * 256 + threadIdx.x;     // grid covers 116736
  if (i < 192 * 96) {
    int g = i / 96, k = i - g * 96;
    float v = (k < 64) ? W_hh[g * 64 + k] : ((k < 70) ? W_ih[g * 6 + (k - 64)] : 0.f);
    Wf[i] = (_Float16)v;
  }
  int j = i - 192 * 96;
  if (j >= 0 && j < 32768) {
    int kt = j >> 11, ntl = (j >> 10) & 1, kf = (j >> 9) & 1;
    int lane = (j >> 3) & 63, e = j & 7;
    int q = lane >> 4, c = lane & 15;
    int row = kt * 32 + ntl * 16 + c;
    int h = kf * 32 + q * 8 + e;
    w1p[j] = (_Float16)w1[row * 64 + h];
  }
  int l = j - 32768;
  if (l >= 0 && l < 65536) {
    int kt = l >> 12, nt = (l >> 9) & 7;
    int lane = (l >> 3) & 63, e = l & 7;
    int q = lane >> 4, c = lane & 15;
    int row = nt * 16 + c;
    int k = kt * 32 + q * 8 + e;
    w2p[l] = (_Float16)w2[row * 512 + k];
  }
}

// ---------------------------------------------------------------- GRU via MFMA
// (unchanged this round)
__global__ __launch_bounds__(256, 1) void gru_kernel(
    const float* __restrict__ x, const _Float16* __restrict__ Wf,
    const float* __restrict__ b_ih, const float* __restrict__ b_hh,
    _Float16* __restrict__ sx) {
  __shared__ __align__(16) _Float16 hist[32][16][72];  // 72 KB
  __shared__ __align__(16) _Float16 xs[Tdim][16][8];   // 32 KB
  const int tid = threadIdx.x;
  const int lane = tid & 63;
  const int w = tid >> 6;                     // wave id 0..3
  const int c = lane & 15;                    // MFMA col = row index
  const int q = lane >> 4;                    // quad

  // ---- preload x for this block's 16 rows, pre-converted to fp16
  for (int i = 0; i < 8; i++) {
    int idx = i * 256 + tid;                  // 0..2047 = (t, row)
    int t = idx >> 4, row = idx & 15;
    int nr = blockIdx.x * 16 + row;           // n = z*32 + b
    const float* p = x + (size_t)(nr & 31) * (Tdim * Zdim * Sdim)
                       + (size_t)t * (Zdim * Sdim) + (size_t)(nr >> 5) * Sdim;
    f16x8 v;
    v[0] = (_Float16)p[0]; v[1] = (_Float16)p[1]; v[2] = (_Float16)p[2];
    v[3] = (_Float16)p[3]; v[4] = (_Float16)p[4]; v[5] = (_Float16)p[5];
    v[6] = (_Float16)0.f;  v[7] = (_Float16)0.f;
    *(f16x8*)&xs[t][row][0] = v;
  }

  const int gr0 = w * 16;                     // r-gate tile base
  const int gz0 = 64 + w * 16;                // z-gate tile base
  const int gn0 = 128 + w * 16;               // n-gate tile base

  // A-frags: A[m=c][k=q*8+j] per 16-gate tile, K=96 fused [h|x|0]
  f16x8 Ar[3], Az[3], Anh[2], Ani;
#pragma unroll
  for (int kf = 0; kf < 3; kf++) {
    Ar[kf] = *(const f16x8*)(Wf + (size_t)(gr0 + c) * 96 + kf * 32 + q * 8);
    Az[kf] = *(const f16x8*)(Wf + (size_t)(gz0 + c) * 96 + kf * 32 + q * 8);
  }
  Anh[0] = *(const f16x8*)(Wf + (size_t)(gn0 + c) * 96 + q * 8);
  Anh[1] = *(const f16x8*)(Wf + (size_t)(gn0 + c) * 96 + 32 + q * 8);
  Ani    = *(const f16x8*)(Wf + (size_t)(gn0 + c) * 96 + 64 + q * 8);

  // biases in D-layout (gate-local m = q*4 + r)
  f32x4 Cr, Cz, Cnh, Cni;
  {
    f32x4 bir = *(const f32x4*)(b_ih + gr0 + q * 4);
    f32x4 bhr = *(const f32x4*)(b_hh + gr0 + q * 4);
    f32x4 biz = *(const f32x4*)(b_ih + gz0 + q * 4);
    f32x4 bhz = *(const f32x4*)(b_hh + gz0 + q * 4);
#pragma unroll
    for (int r = 0; r < 4; r++) { Cr[r] = bir[r] + bhr[r]; Cz[r] = biz[r] + bhz[r]; }
    Cnh = *(const f32x4*)(b_hh + gn0 + q * 4);
    Cni = *(const f32x4*)(b_ih + gn0 + q * 4);
  }

  __syncthreads();                            // xs ready

  f16x8 Bh0 = {0, 0, 0, 0, 0, 0, 0, 0};
  f16x8 Bh1 = {0, 0, 0, 0, 0, 0, 0, 0};
  f32x4 hprev = {0.f, 0.f, 0.f, 0.f};

  // ---- pipeline seeds for t=0: x-projection MFMAs
  f32x4 Dr_s, Dz_s, Dni_s;
  {
    f16x8 xv8 = *(const f16x8*)&xs[0][c][0];
    f16x8 Bx;
#pragma unroll
    for (int j = 0; j < 8; j++) Bx[j] = (q == 0) ? xv8[j] : (_Float16)0.f;
    Dni_s = __builtin_amdgcn_mfma_f32_16x16x32_f16(Ani, Bx, Cni, 0, 0, 0);
    Dr_s  = __builtin_amdgcn_mfma_f32_16x16x32_f16(Ar[2], Bx, Cr, 0, 0, 0);
    Dz_s  = __builtin_amdgcn_mfma_f32_16x16x32_f16(Az[2], Bx, Cz, 0, 0, 0);
  }

#pragma unroll 1
  for (int tch = 0; tch < 4; tch++) {
#pragma unroll 1
    for (int tc = 0; tc < 32; tc++) {
      const int t = tch * 32 + tc;
      // ---- h-dependent MFMAs (2 dep stages), seeded with x-projection
      f32x4 Dnh = __builtin_amdgcn_mfma_f32_16x16x32_f16(Anh[0], Bh0, Cnh, 0, 0, 0);
      f32x4 Dr  = __builtin_amdgcn_mfma_f32_16x16x32_f16(Ar[0], Bh0, Dr_s, 0, 0, 0);
      f32x4 Dz  = __builtin_amdgcn_mfma_f32_16x16x32_f16(Az[0], Bh0, Dz_s, 0, 0, 0);
      Dnh = __builtin_amdgcn_mfma_f32_16x16x32_f16(Anh[1], Bh1, Dnh, 0, 0, 0);
      Dr  = __builtin_amdgcn_mfma_f32_16x16x32_f16(Ar[1], Bh1, Dr, 0, 0, 0);
      Dz  = __builtin_amdgcn_mfma_f32_16x16x32_f16(Az[1], Bh1, Dz, 0, 0, 0);

      f16x4 pk;
#pragma unroll
      for (int r = 0; r < 4; r++) {
        float rr = sigmoidf_fast(Dr[r]);
        float zg = sigmoidf_fast(Dz[r]);
        float nn = tanhf_fast(Dni_s[r] + rr * Dnh[r]);
        float hnew = nn + zg * (hprev[r] - nn);
        hprev[r] = hnew;
        pk[r] = (_Float16)hnew;
      }
      *(f16x4*)&hist[tc][c][w * 16 + q * 4] = pk;

      // ---- pre-barrier: x-projection for t+1 (h-independent, hides behind skew)
      if (t + 1 < Tdim) {
        f16x8 xv8 = *(const f16x8*)&xs[t + 1][c][0];
        f16x8 Bx;
#pragma unroll
        for (int j = 0; j < 8; j++) Bx[j] = (q == 0) ? xv8[j] : (_Float16)0.f;
        Dni_s = __builtin_amdgcn_mfma_f32_16x16x32_f16(Ani, Bx, Cni, 0, 0, 0);
        Dr_s  = __builtin_amdgcn_mfma_f32_16x16x32_f16(Ar[2], Bx, Cr, 0, 0, 0);
        Dz_s  = __builtin_amdgcn_mfma_f32_16x16x32_f16(Az[2], Bx, Cz, 0, 0, 0);
      }
      __syncthreads();                        // lgkm-only drain
      Bh0 = *(const f16x8*)&hist[tc][c][q * 8];
      Bh1 = *(const f16x8*)&hist[tc][c][32 + q * 8];
    }
    // coalesced dump of the 32-step chunk; wave w handles rows 4w..4w+3
    {
      const int t0 = tch * 32;
#pragma unroll
      for (int rr2 = 0; rr2 < 4; rr2++) {
        const int row = w * 4 + rr2;
        const int nrow = blockIdx.x * 16 + row;
        _Float16* dst = sx + (size_t)nrow * Tdim * Hdim + (size_t)t0 * Hdim;
#pragma unroll
        for (int it = 0; it < 4; it++) {
          int idx = it * 64 + lane;           // 0..255
          int tcc = idx >> 3, hd8 = idx & 7;
          f16x8 vv = *(const f16x8*)&hist[tcc][row][hd8 * 8];
          *(f16x8*)(dst + tcc * 64 + hd8 * 8) = vv;  // lane-contiguous 1 KB/iter
        }
      }
      __syncthreads();                        // dump reads done before hist reuse
    }
  }
}

// ---------------------------------------------------------------- fused MLP v2
// Block = 4 waves / 256 rows; wave = 64 rows (4 groups of 16).
// - ALL of w1 staged to LDS once (64 KB, one barrier total).
// - w2 A-frags read DIRECTLY from global each kt (frag-linear, L2-resident):
//   no per-kt staging commits, no per-kt barrier, waves fully independent.
// - rep (a1 D->B transpose) software-pipelined across kt: iteration kt reads
//   Ba(kt) written last iteration, computes layer1(kt+1), then layer2(kt) --
//   the rep write->read turnaround spans 32 L2-MFMAs, off the critical path.
// LDS = 64 + 16 = 80 KB -> 2 blocks/CU (VGPR-capped anyway).
__global__ __launch_bounds__(256, 2) void mlp_kernel(
    const _Float16* __restrict__ sx, const _Float16* __restrict__ w1p,
    const _Float16* __restrict__ w2p, const float* __restrict__ b1,
    const float* __restrict__ b2, const float* __restrict__ w3,
    const float* __restrict__ b3, float* __restrict__ out) {
  __shared__ __align__(16) _Float16 w1s[32768];        // 64 KB: all w1 frags
  __shared__ __align__(16) _Float16 rep[4][4][512];    // 16 KB [wave][g][...]
  const int tid = threadIdx.x;
  const int lane = tid & 63;
  const int wave = tid >> 6;
  const int c = lane & 15;
  const int q = lane >> 4;
  const size_t m0 = ((size_t)blockIdx.x * 4 + wave) * 64;

  // ---- stage all of w1 into LDS (one time; 64 KB/block from L2/L3)
  {
    const u32x4* src = (const u32x4*)w1p;   // 4096 u32x4
    u32x4* dst = (u32x4*)w1s;
#pragma unroll
    for (int i = 0; i < 16; i++)
      dst[i * 256 + tid] = src[i * 256 + tid];
  }

  // ---- resident activations (rows) as B-frags for the whole kernel
  f16x8 Bs[4][2];
#pragma unroll
  for (int g = 0; g < 4; g++)
#pragma unroll
    for (int kk = 0; kk < 2; kk++)
      Bs[g][kk] = *(const f16x8*)(sx + (m0 + g * 16 + c) * Hdim + kk * 32 + q * 8);

  f32x4 acc2[4][8];
#pragma unroll
  for (int g = 0; g < 4; g++)
#pragma unroll
    for (int nt = 0; nt < 8; nt++) acc2[g][nt] = (f32x4){0.f, 0.f, 0.f, 0.f};

  __syncthreads();                            // w1s ready (only barrier)

  // ---- prologue: layer1 for kt=0 into rep
  {
#pragma unroll
    for (int ntl = 0; ntl < 2; ntl++) {
      f16x8 A0 = *(const f16x8*)&w1s[ntl * 1024 + lane * 8];
      f16x8 A1 = *(const f16x8*)&w1s[ntl * 1024 + 512 + lane * 8];
      f32x4 bb = *(const f32x4*)(b1 + ntl * 16 + q * 4);
      const int roff = ((2 * ntl + (q >> 1)) * 16 + c) * 8 + (q & 1) * 4;
#pragma unroll
      for (int g = 0; g < 4; g++) {
        f32x4 cc = __builtin_amdgcn_mfma_f32_16x16x32_f16(A0, Bs[g][0], bb, 0, 0, 0);
        cc = __builtin_amdgcn_mfma_f32_16x16x32_f16(A1, Bs[g][1], cc, 0, 0, 0);
        f16x4 pk;
#pragma unroll
        for (int r = 0; r < 4; r++)
          pk[r] = (_Float16)(cc[r] > 0.f ? cc[r] : 0.f);
        *(f16x4*)&rep[wave][g][roff] = pk;
      }
    }
  }

#pragma unroll 1
  for (int kt = 0; kt < 16; kt++) {
    const int ktn = kt + 1;
    const bool more = (ktn < 16);
    // ---- issue ALL loads up front (latency hidden under MFMAs below)
    f16x8 A2[8];                              // layer2 weights for kt (global)
#pragma unroll
    for (int nt = 0; nt < 8; nt++)
      A2[nt] = *(const f16x8*)(w2p + (size_t)kt * 4096 + nt * 512 + lane * 8);
    f16x8 W0[2], W1[2];                       // layer1 weights for kt+1 (LDS)
    f32x4 bb[2];
    {
      const int kts = more ? ktn : kt;        // harmless re-read on last iter
#pragma unroll
      for (int ntl = 0; ntl < 2; ntl++) {
        W0[ntl] = *(const f16x8*)&w1s[kts * 2048 + ntl * 1024 + lane * 8];
        W1[ntl] = *(const f16x8*)&w1s[kts * 2048 + ntl * 1024 + 512 + lane * 8];
        bb[ntl] = *(const f32x4*)(b1 + kts * 32 + ntl * 16 + q * 4);
      }
    }
    f16x8 Ba[4];                              // a1(kt), written last iteration
#pragma unroll
    for (int g = 0; g < 4; g++)
      Ba[g] = *(const f16x8*)&rep[wave][g][lane * 8];

    // ---- layer1 for kt+1 -> rep (WAR on Ba covered by the read->write gap)
    if (more) {
#pragma unroll
      for (int ntl = 0; ntl < 2; ntl++) {
        const int roff = ((2 * ntl + (q >> 1)) * 16 + c) * 8 + (q & 1) * 4;
#pragma unroll
        for (int g = 0; g < 4; g++) {
          f32x4 cc = __builtin_amdgcn_mfma_f32_16x16x32_f16(W0[ntl], Bs[g][0], bb[ntl], 0, 0, 0);
          cc = __builtin_amdgcn_mfma_f32_16x16x32_f16(W1[ntl], Bs[g][1], cc, 0, 0, 0);
          f16x4 pk;
#pragma unroll
          for (int r = 0; r < 4; r++)
            pk[r] = (_Float16)(cc[r] > 0.f ? cc[r] : 0.f);
          *(f16x4*)&rep[wave][g][roff] = pk;
        }
      }
    }

    // ---- layer2 partial for kt
#pragma unroll
    for (int nt = 0; nt < 8; nt++)
#pragma unroll
      for (int g = 0; g < 4; g++)
        acc2[g][nt] = __builtin_amdgcn_mfma_f32_16x16x32_f16(A2[nt], Ba[g], acc2[g][nt], 0, 0, 0);
  }

  // ---- layer3: out[row] = sum relu(a2 + b2) * w3 + b3
  float part[4] = {0.f, 0.f, 0.f, 0.f};
#pragma unroll
  for (int nt = 0; nt < 8; nt++) {
    f32x4 bb = *(const f32x4*)(b2 + nt * 16 + q * 4);
    f32x4 ww = *(const f32x4*)(w3 + nt * 16 + q * 4);
#pragma unroll
    for (int g = 0; g < 4; g++) {
#pragma unroll
      for (int r = 0; r < 4; r++) {
        float v = acc2[g][nt][r] + bb[r];
        v = v > 0.f ? v : 0.f;
        part[g] = fmaf(v, ww[r], part[g]);
      }
    }
  }
#pragma unroll
  for (int g = 0; g < 4; g++) {
    part[g] += __shfl_xor(part[g], 16, 64);
    part[g] += __shfl_xor(part[g], 32, 64);
  }
  // lane (c,q) writes row q*16+c of this wave's 64 rows
  float pv = (q == 0) ? part[0] : (q == 1) ? part[1] : (q == 2) ? part[2] : part[3];
  out[m0 + q * 16 + c] = pv + b3[0];
}

// ----------------------------------------------------------------
extern "C" void kernel_launch(void* const* d_in, const int* in_sizes, int n_in,
                              void* d_out, int out_size, void* d_ws, size_t ws_size,
                              hipStream_t stream) {
  const float* x    = (const float*)d_in[0];
  const float* W_ih = (const float*)d_in[1];
  const float* W_hh = (const float*)d_in[2];
  const float* b_ih = (const float*)d_in[3];
  const float* b_hh = (const float*)d_in[4];
  const float* w1   = (const float*)d_in[5];
  const float* b1   = (const float*)d_in[6];
  const float* w2   = (const float*)d_in[7];
  const float* b2   = (const float*)d_in[8];
  const float* w3   = (const float*)d_in[9];
  const float* b3   = (const float*)d_in[10];
  float* out = (float*)d_out;

  char* ws = (char*)d_ws;
  _Float16* sxf = (_Float16*)ws;                          // 52,428,800 B
  _Float16* Wf  = (_Float16*)(ws + 52428800);             // 36,864 B
  _Float16* w1p = (_Float16*)(ws + 52428800 + 36864);     // 65,536 B
  _Float16* w2p = (_Float16*)(ws + 52428800 + 36864 + 65536); // 131,072 B

  hipLaunchKernelGGL(prep_kernel, dim3(456), dim3(256), 0, stream,
                     W_ih, W_hh, w1, w2, Wf, w1p, w2p);
  hipLaunchKernelGGL(gru_kernel, dim3(ZB / 16), dim3(256), 0, stream,
                     x, Wf, b_ih, b_hh, sxf);
  hipLaunchKernelGGL(mlp_kernel, dim3(Mrows / 256), dim3(256), 0, stream,
                     sxf, w1p, w2p, b1, b2, w3, b3, out);
}

// Round 2
// 239.780 us; speedup vs baseline: 1.0523x; 1.0334x over previous
//
#include <hip/hip_runtime.h>
#include <stdint.h>

#define Tdim 128
#define Zdim 100
#define Sdim 6
#define Hdim 64
#define ZB   3200           // Z*B
#define F1   512
#define F2   128
#define Mrows (ZB * Tdim)   // 409600

typedef _Float16 f16x8 __attribute__((ext_vector_type(8)));
typedef _Float16 f16x4 __attribute__((ext_vector_type(4)));
typedef float f32x4 __attribute__((ext_vector_type(4)));
typedef uint32_t u32x4 __attribute__((ext_vector_type(4)));

__device__ __forceinline__ float fast_rcp(float x) {
  return __builtin_amdgcn_rcpf(x);   // v_rcp_f32: 1 trans op, no div-fixup chain
}

// ---------------------------------------------------------------- prep
// Wf[192][96] fp16: [W_hh | W_ih | 0] per gate (K=96 fused), for the GRU.
// w1p frag-linear: [kt][ntl][kfrag][lane][8].  32768 f16.
// w2p frag-linear: [kt][nt][lane][8].          65536 f16.
__global__ __launch_bounds__(256) void prep_kernel(
    const float* __restrict__ W_ih, const float* __restrict__ W_hh,
    const float* __restrict__ w1, const float* __restrict__ w2,
    _Float16* __restrict__ Wf, _Float16* __restrict__ w1p,
    _Float16* __restrict__ w2p) {
  int i = blockIdx.x * 256 + threadIdx.x;     // grid covers 116736
  if (i < 192 * 96) {
    int g = i / 96, k = i - g * 96;
    float v = (k < 64) ? W_hh[g * 64 + k] : ((k < 70) ? W_ih[g * 6 + (k - 64)] : 0.f);
    Wf[i] = (_Float16)v;
  }
  int j = i - 192 * 96;
  if (j >= 0 && j < 32768) {
    int kt = j >> 11, ntl = (j >> 10) & 1, kf = (j >> 9) & 1;
    int lane = (j >> 3) & 63, e = j & 7;
    int q = lane >> 4, c = lane & 15;
    int row = kt * 32 + ntl * 16 + c;
    int h = kf * 32 + q * 8 + e;
    w1p[j] = (_Float16)w1[row * 64 + h];
  }
  int l = j - 32768;
  if (l >= 0 && l < 65536) {
    int kt = l >> 12, nt = (l >> 9) & 7;
    int lane = (l >> 3) & 63, e = l & 7;
    int q = lane >> 4, c = lane & 15;
    int row = nt * 16 + c;
    int k = kt * 32 + q * 8 + e;
    w2p[l] = (_Float16)w2[row * 512 + k];
  }
}

// ---------------------------------------------------------------- GRU via MFMA v2
// 512 threads = 8 waves = TWO independent 16-row streams (waves 0-3: rows
// 0-15, waves 4-7: rows 16-31) -> 2 independent waves/SIMD so dep-chain
// stalls of one stream are filled by the other (was 1 wave/SIMD, everything
// exposed). Grid = 100 blocks.
// Activation uses v_rcp (no precise-div fixup chains) and the x-operand
// masking is 4 v_and on u32 instead of 8 f16 cndmasks.
// hist chunk reduced 32->16 steps so 2-stream LDS fits: 72+64 = 136 KB.
__global__ __launch_bounds__(512, 1) void gru_kernel(
    const float* __restrict__ x, const _Float16* __restrict__ Wf,
    const float* __restrict__ b_ih, const float* __restrict__ b_hh,
    _Float16* __restrict__ sx) {
  __shared__ __align__(16) _Float16 hist[16][32][72];  // 72 KB (16-step chunk)
  __shared__ __align__(16) _Float16 xs[Tdim][32][8];   // 64 KB
  const int tid = threadIdx.x;
  const int lane = tid & 63;
  const int w8 = tid >> 6;                    // wave id 0..7
  const int s = w8 >> 2;                      // stream 0/1
  const int w = w8 & 3;                       // gate-tile wave within stream
  const int c = lane & 15;                    // MFMA col = row index
  const int q = lane >> 4;                    // quad
  const int s16c = s * 16 + c;                // row slot in hist/xs

  // ---- preload x for this block's 32 rows, pre-converted to fp16
  for (int i = 0; i < 8; i++) {
    int idx = i * 512 + tid;                  // 0..4095 = (t, row)
    int t = idx >> 5, row = idx & 31;
    int nr = blockIdx.x * 32 + row;           // n = z*32 + b
    const float* p = x + (size_t)(nr & 31) * (Tdim * Zdim * Sdim)
                       + (size_t)t * (Zdim * Sdim) + (size_t)(nr >> 5) * Sdim;
    f16x8 v;
    v[0] = (_Float16)p[0]; v[1] = (_Float16)p[1]; v[2] = (_Float16)p[2];
    v[3] = (_Float16)p[3]; v[4] = (_Float16)p[4]; v[5] = (_Float16)p[5];
    v[6] = (_Float16)0.f;  v[7] = (_Float16)0.f;
    *(f16x8*)&xs[t][row][0] = v;
  }

  const int gr0 = w * 16;                     // r-gate tile base
  const int gz0 = 64 + w * 16;                // z-gate tile base
  const int gn0 = 128 + w * 16;               // n-gate tile base

  // A-frags: A[m=c][k=q*8+j] per 16-gate tile, K=96 fused [h|x|0]
  f16x8 Ar[3], Az[3], Anh[2], Ani;
#pragma unroll
  for (int kf = 0; kf < 3; kf++) {
    Ar[kf] = *(const f16x8*)(Wf + (size_t)(gr0 + c) * 96 + kf * 32 + q * 8);
    Az[kf] = *(const f16x8*)(Wf + (size_t)(gz0 + c) * 96 + kf * 32 + q * 8);
  }
  Anh[0] = *(const f16x8*)(Wf + (size_t)(gn0 + c) * 96 + q * 8);
  Anh[1] = *(const f16x8*)(Wf + (size_t)(gn0 + c) * 96 + 32 + q * 8);
  Ani    = *(const f16x8*)(Wf + (size_t)(gn0 + c) * 96 + 64 + q * 8);

  // biases in D-layout (gate-local m = q*4 + r)
  f32x4 Cr, Cz, Cnh, Cni;
  {
    f32x4 bir = *(const f32x4*)(b_ih + gr0 + q * 4);
    f32x4 bhr = *(const f32x4*)(b_hh + gr0 + q * 4);
    f32x4 biz = *(const f32x4*)(b_ih + gz0 + q * 4);
    f32x4 bhz = *(const f32x4*)(b_hh + gz0 + q * 4);
#pragma unroll
    for (int r = 0; r < 4; r++) { Cr[r] = bir[r] + bhr[r]; Cz[r] = biz[r] + bhz[r]; }
    Cnh = *(const f32x4*)(b_hh + gn0 + q * 4);
    Cni = *(const f32x4*)(b_ih + gn0 + q * 4);
  }

  // mask for the x B-operand: only k=0..7 rows (q==0 lanes) are nonzero
  const uint32_t xmask = (q == 0) ? 0xffffffffu : 0u;

  __syncthreads();                            // xs ready

  f16x8 Bh0 = {0, 0, 0, 0, 0, 0, 0, 0};
  f16x8 Bh1 = {0, 0, 0, 0, 0, 0, 0, 0};
  f32x4 hprev = {0.f, 0.f, 0.f, 0.f};

  // ---- pipeline seeds for t=0: x-projection MFMAs
  f32x4 Dr_s, Dz_s, Dni_s;
  {
    u32x4 xv = *(const u32x4*)&xs[0][s16c][0];
    xv[0] &= xmask; xv[1] &= xmask; xv[2] &= xmask; xv[3] &= xmask;
    f16x8 Bx = *(f16x8*)&xv;
    Dni_s = __builtin_amdgcn_mfma_f32_16x16x32_f16(Ani, Bx, Cni, 0, 0, 0);
    Dr_s  = __builtin_amdgcn_mfma_f32_16x16x32_f16(Ar[2], Bx, Cr, 0, 0, 0);
    Dz_s  = __builtin_amdgcn_mfma_f32_16x16x32_f16(Az[2], Bx, Cz, 0, 0, 0);
  }

#pragma unroll 1
  for (int tch = 0; tch < 8; tch++) {
#pragma unroll 1
    for (int tc = 0; tc < 16; tc++) {
      const int t = tch * 16 + tc;
      // ---- h-dependent MFMAs (2 dep stages), seeded with x-projection
      f32x4 Dnh = __builtin_amdgcn_mfma_f32_16x16x32_f16(Anh[0], Bh0, Cnh, 0, 0, 0);
      f32x4 Dr  = __builtin_amdgcn_mfma_f32_16x16x32_f16(Ar[0], Bh0, Dr_s, 0, 0, 0);
      f32x4 Dz  = __builtin_amdgcn_mfma_f32_16x16x32_f16(Az[0], Bh0, Dz_s, 0, 0, 0);
      Dnh = __builtin_amdgcn_mfma_f32_16x16x32_f16(Anh[1], Bh1, Dnh, 0, 0, 0);
      Dr  = __builtin_amdgcn_mfma_f32_16x16x32_f16(Ar[1], Bh1, Dr, 0, 0, 0);
      Dz  = __builtin_amdgcn_mfma_f32_16x16x32_f16(Az[1], Bh1, Dz, 0, 0, 0);

      f16x4 pk;
#pragma unroll
      for (int r = 0; r < 4; r++) {
        float er = __expf(-Dr[r]);
        float rr = fast_rcp(1.f + er);        // sigmoid, no div-fixup
        float ez = __expf(-Dz[r]);
        float zg = fast_rcp(1.f + ez);
        float na = Dni_s[r] + rr * Dnh[r];
        float en = __expf(2.f * na);
        float nn = 1.f - 2.f * fast_rcp(en + 1.f);  // tanh
        float hnew = nn + zg * (hprev[r] - nn);
        hprev[r] = hnew;
        pk[r] = (_Float16)hnew;
      }
      *(f16x4*)&hist[tc][s16c][w * 16 + q * 4] = pk;

      // ---- pre-barrier: x-projection for t+1 (h-independent, hides behind skew)
      if (t + 1 < Tdim) {
        u32x4 xv = *(const u32x4*)&xs[t + 1][s16c][0];
        xv[0] &= xmask; xv[1] &= xmask; xv[2] &= xmask; xv[3] &= xmask;
        f16x8 Bx = *(f16x8*)&xv;
        Dni_s = __builtin_amdgcn_mfma_f32_16x16x32_f16(Ani, Bx, Cni, 0, 0, 0);
        Dr_s  = __builtin_amdgcn_mfma_f32_16x16x32_f16(Ar[2], Bx, Cr, 0, 0, 0);
        Dz_s  = __builtin_amdgcn_mfma_f32_16x16x32_f16(Az[2], Bx, Cz, 0, 0, 0);
      }
      __syncthreads();                        // h exchange across the 4 gate waves
      Bh0 = *(const f16x8*)&hist[tc][s16c][q * 8];
      Bh1 = *(const f16x8*)&hist[tc][s16c][32 + q * 8];
    }
    // coalesced dump of the 16-step chunk; wave w8 handles rows 4*w8..4*w8+3
    {
      const int t0 = tch * 16;
#pragma unroll
      for (int rr2 = 0; rr2 < 4; rr2++) {
        const int row = w8 * 4 + rr2;
        const int nrow = blockIdx.x * 32 + row;
        _Float16* dst = sx + (size_t)nrow * Tdim * Hdim + (size_t)t0 * Hdim;
#pragma unroll
        for (int it = 0; it < 2; it++) {
          int idx = it * 64 + lane;           // 0..127
          int tcc = idx >> 3, hd8 = idx & 7;
          f16x8 vv = *(const f16x8*)&hist[tcc][row][hd8 * 8];
          *(f16x8*)(dst + tcc * 64 + hd8 * 8) = vv;  // lane-contiguous 1 KB/iter
        }
      }
      __syncthreads();                        // dump reads done before hist reuse
    }
  }
}

// ---------------------------------------------------------------- fused MLP v2
// Block = 4 waves / 256 rows; wave = 64 rows (4 groups of 16).
// - ALL of w1 staged to LDS once (64 KB, one barrier total).
// - w2 A-frags read DIRECTLY from global each kt (frag-linear, L2-resident).
// - rep (a1 D->B transpose) software-pipelined across kt.
__global__ __launch_bounds__(256, 2) void mlp_kernel(
    const _Float16* __restrict__ sx, const _Float16* __restrict__ w1p,
    const _Float16* __restrict__ w2p, const float* __restrict__ b1,
    const float* __restrict__ b2, const float* __restrict__ w3,
    const float* __restrict__ b3, float* __restrict__ out) {
  __shared__ __align__(16) _Float16 w1s[32768];        // 64 KB: all w1 frags
  __shared__ __align__(16) _Float16 rep[4][4][512];    // 16 KB [wave][g][...]
  const int tid = threadIdx.x;
  const int lane = tid & 63;
  const int wave = tid >> 6;
  const int c = lane & 15;
  const int q = lane >> 4;
  const size_t m0 = ((size_t)blockIdx.x * 4 + wave) * 64;

  // ---- stage all of w1 into LDS (one time; 64 KB/block from L2/L3)
  {
    const u32x4* src = (const u32x4*)w1p;   // 4096 u32x4
    u32x4* dst = (u32x4*)w1s;
#pragma unroll
    for (int i = 0; i < 16; i++)
      dst[i * 256 + tid] = src[i * 256 + tid];
  }

  // ---- resident activations (rows) as B-frags for the whole kernel
  f16x8 Bs[4][2];
#pragma unroll
  for (int g = 0; g < 4; g++)
#pragma unroll
    for (int kk = 0; kk < 2; kk++)
      Bs[g][kk] = *(const f16x8*)(sx + (m0 + g * 16 + c) * Hdim + kk * 32 + q * 8);

  f32x4 acc2[4][8];
#pragma unroll
  for (int g = 0; g < 4; g++)
#pragma unroll
    for (int nt = 0; nt < 8; nt++) acc2[g][nt] = (f32x4){0.f, 0.f, 0.f, 0.f};

  __syncthreads();                            // w1s ready (only barrier)

  // ---- prologue: layer1 for kt=0 into rep
  {
#pragma unroll
    for (int ntl = 0; ntl < 2; ntl++) {
      f16x8 A0 = *(const f16x8*)&w1s[ntl * 1024 + lane * 8];
      f16x8 A1 = *(const f16x8*)&w1s[ntl * 1024 + 512 + lane * 8];
      f32x4 bb = *(const f32x4*)(b1 + ntl * 16 + q * 4);
      const int roff = ((2 * ntl + (q >> 1)) * 16 + c) * 8 + (q & 1) * 4;
#pragma unroll
      for (int g = 0; g < 4; g++) {
        f32x4 cc = __builtin_amdgcn_mfma_f32_16x16x32_f16(A0, Bs[g][0], bb, 0, 0, 0);
        cc = __builtin_amdgcn_mfma_f32_16x16x32_f16(A1, Bs[g][1], cc, 0, 0, 0);
        f16x4 pk;
#pragma unroll
        for (int r = 0; r < 4; r++)
          pk[r] = (_Float16)(cc[r] > 0.f ? cc[r] : 0.f);
        *(f16x4*)&rep[wave][g][roff] = pk;
      }
    }
  }

#pragma unroll 1
  for (int kt = 0; kt < 16; kt++) {
    const int ktn = kt + 1;
    const bool more = (ktn < 16);
    // ---- issue ALL loads up front (latency hidden under MFMAs below)
    f16x8 A2[8];                              // layer2 weights for kt (global)
#pragma unroll
    for (int nt = 0; nt < 8; nt++)
      A2[nt] = *(const f16x8*)(w2p + (size_t)kt * 4096 + nt * 512 + lane * 8);
    f16x8 W0[2], W1[2];                       // layer1 weights for kt+1 (LDS)
    f32x4 bb[2];
    {
      const int kts = more ? ktn : kt;        // harmless re-read on last iter
#pragma unroll
      for (int ntl = 0; ntl < 2; ntl++) {
        W0[ntl] = *(const f16x8*)&w1s[kts * 2048 + ntl * 1024 + lane * 8];
        W1[ntl] = *(const f16x8*)&w1s[kts * 2048 + ntl * 1024 + 512 + lane * 8];
        bb[ntl] = *(const f32x4*)(b1 + kts * 32 + ntl * 16 + q * 4);
      }
    }
    f16x8 Ba[4];                              // a1(kt), written last iteration
#pragma unroll
    for (int g = 0; g < 4; g++)
      Ba[g] = *(const f16x8*)&rep[wave][g][lane * 8];

    // ---- layer1 for kt+1 -> rep (WAR on Ba covered by the read->write gap)
    if (more) {
#pragma unroll
      for (int ntl = 0; ntl < 2; ntl++) {
        const int roff = ((2 * ntl + (q >> 1)) * 16 + c) * 8 + (q & 1) * 4;
#pragma unroll
        for (int g = 0; g < 4; g++) {
          f32x4 cc = __builtin_amdgcn_mfma_f32_16x16x32_f16(W0[ntl], Bs[g][0], bb[ntl], 0, 0, 0);
          cc = __builtin_amdgcn_mfma_f32_16x16x32_f16(W1[ntl], Bs[g][1], cc, 0, 0, 0);
          f16x4 pk;
#pragma unroll
          for (int r = 0; r < 4; r++)
            pk[r] = (_Float16)(cc[r] > 0.f ? cc[r] : 0.f);
          *(f16x4*)&rep[wave][g][roff] = pk;
        }
      }
    }

    // ---- layer2 partial for kt
#pragma unroll
    for (int nt = 0; nt < 8; nt++)
#pragma unroll
      for (int g = 0; g < 4; g++)
        acc2[g][nt] = __builtin_amdgcn_mfma_f32_16x16x32_f16(A2[nt], Ba[g], acc2[g][nt], 0, 0, 0);
  }

  // ---- layer3: out[row] = sum relu(a2 + b2) * w3 + b3
  float part[4] = {0.f, 0.f, 0.f, 0.f};
#pragma unroll
  for (int nt = 0; nt < 8; nt++) {
    f32x4 bb = *(const f32x4*)(b2 + nt * 16 + q * 4);
    f32x4 ww = *(const f32x4*)(w3 + nt * 16 + q * 4);
#pragma unroll
    for (int g = 0; g < 4; g++) {
#pragma unroll
      for (int r = 0; r < 4; r++) {
        float v = acc2[g][nt][r] + bb[r];
        v = v > 0.f ? v : 0.f;
        part[g] = fmaf(v, ww[r], part[g]);
      }
    }
  }
#pragma unroll
  for (int g = 0; g < 4; g++) {
    part[g] += __shfl_xor(part[g], 16, 64);
    part[g] += __shfl_xor(part[g], 32, 64);
  }
  // lane (c,q) writes row q*16+c of this wave's 64 rows
  float pv = (q == 0) ? part[0] : (q == 1) ? part[1] : (q == 2) ? part[2] : part[3];
  out[m0 + q * 16 + c] = pv + b3[0];
}

// ----------------------------------------------------------------
extern "C" void kernel_launch(void* const* d_in, const int* in_sizes, int n_in,
                              void* d_out, int out_size, void* d_ws, size_t ws_size,
                              hipStream_t stream) {
  const float* x    = (const float*)d_in[0];
  const float* W_ih = (const float*)d_in[1];
  const float* W_hh = (const float*)d_in[2];
  const float* b_ih = (const float*)d_in[3];
  const float* b_hh = (const float*)d_in[4];
  const float* w1   = (const float*)d_in[5];
  const float* b1   = (const float*)d_in[6];
  const float* w2   = (const float*)d_in[7];
  const float* b2   = (const float*)d_in[8];
  const float* w3   = (const float*)d_in[9];
  const float* b3   = (const float*)d_in[10];
  float* out = (float*)d_out;

  char* ws = (char*)d_ws;
  _Float16* sxf = (_Float16*)ws;                          // 52,428,800 B
  _Float16* Wf  = (_Float16*)(ws + 52428800);             // 36,864 B
  _Float16* w1p = (_Float16*)(ws + 52428800 + 36864);     // 65,536 B
  _Float16* w2p = (_Float16*)(ws + 52428800 + 36864 + 65536); // 131,072 B

  hipLaunchKernelGGL(prep_kernel, dim3(456), dim3(256), 0, stream,
                     W_ih, W_hh, w1, w2, Wf, w1p, w2p);
  hipLaunchKernelGGL(gru_kernel, dim3(ZB / 32), dim3(512), 0, stream,
                     x, Wf, b_ih, b_hh, sxf);
  hipLaunchKernelGGL(mlp_kernel, dim3(Mrows / 256), dim3(256), 0, stream,
                     sxf, w1p, w2p, b1, b2, w3, b3, out);
}

// Round 3
// 229.304 us; speedup vs baseline: 1.1004x; 1.0457x over previous
//
#include <hip/hip_runtime.h>
#include <stdint.h>

#define Tdim 128
#define Zdim 100
#define Sdim 6
#define Hdim 64
#define ZB   3200           // Z*B
#define F1   512
#define F2   128
#define Mrows (ZB * Tdim)   // 409600
#define NGRU 100            // gru-role blocks (ZB/32)
#define NMLP 800            // mlp-role blocks (NGRU * 8 chunks)

typedef _Float16 f16x8 __attribute__((ext_vector_type(8)));
typedef _Float16 f16x4 __attribute__((ext_vector_type(4)));
typedef float f32x4 __attribute__((ext_vector_type(4)));
typedef uint32_t u32x4 __attribute__((ext_vector_type(4)));

__device__ __forceinline__ float fast_rcp(float x) {
  return __builtin_amdgcn_rcpf(x);   // v_rcp_f32: 1 trans op, no div-fixup chain
}

// ---------------------------------------------------------------- prep
// Wf[192][96] fp16: [W_hh | W_ih | 0] per gate (K=96 fused), for the GRU.
// w1p frag-linear: [kt][ntl][kfrag][lane][8].  32768 f16.
// w2p frag-linear: [kt][nt][lane][8].          65536 f16.
// Also zeroes the producer-consumer sync area (800 flags + 1 ticket) each
// iteration (workspace is re-poisoned between graph replays).
__global__ __launch_bounds__(256) void prep_kernel(
    const float* __restrict__ W_ih, const float* __restrict__ W_hh,
    const float* __restrict__ w1, const float* __restrict__ w2,
    _Float16* __restrict__ Wf, _Float16* __restrict__ w1p,
    _Float16* __restrict__ w2p, unsigned int* __restrict__ sync) {
  int i = blockIdx.x * 256 + threadIdx.x;     // grid covers 116736
  if (i < 801) sync[i] = 0u;                  // flags[800] + ticket
  if (i < 192 * 96) {
    int g = i / 96, k = i - g * 96;
    float v = (k < 64) ? W_hh[g * 64 + k] : ((k < 70) ? W_ih[g * 6 + (k - 64)] : 0.f);
    Wf[i] = (_Float16)v;
  }
  int j = i - 192 * 96;
  if (j >= 0 && j < 32768) {
    int kt = j >> 11, ntl = (j >> 10) & 1, kf = (j >> 9) & 1;
    int lane = (j >> 3) & 63, e = j & 7;
    int q = lane >> 4, c = lane & 15;
    int row = kt * 32 + ntl * 16 + c;
    int h = kf * 32 + q * 8 + e;
    w1p[j] = (_Float16)w1[row * 64 + h];
  }
  int l = j - 32768;
  if (l >= 0 && l < 65536) {
    int kt = l >> 12, nt = (l >> 9) & 7;
    int lane = (l >> 3) & 63, e = l & 7;
    int q = lane >> 4, c = lane & 15;
    int row = nt * 16 + c;
    int k = kt * 32 + q * 8 + e;
    w2p[l] = (_Float16)w2[row * 512 + k];
  }
}

// ---------------------------------------------------------------- fused GRU+MLP
// One dispatch, 900 blocks x 512 threads, 1 block/CU (136 KB LDS union).
// Role by atomic ticket: first 100 started blocks take GRU (guaranteed
// resident -> deadlock-free); the other 800 are MLP consumers, one per
// (gru-block gb, chunk ch) = 32 seqs x 16 timesteps.
// Producer per chunk: dump sx -> __syncthreads (vmcnt drain) ->
// __threadfence (L2 writeback, agent scope) -> atomicAdd(flag).
// Consumer: stage w1 to LDS, relaxed-spin + acquire on flag, barrier, go.
__global__ __launch_bounds__(512, 2) void fused_kernel(
    const float* __restrict__ x, const _Float16* __restrict__ Wf,
    const float* __restrict__ b_ih, const float* __restrict__ b_hh,
    _Float16* __restrict__ sx, const _Float16* __restrict__ w1p,
    const _Float16* __restrict__ w2p, const float* __restrict__ b1,
    const float* __restrict__ b2, const float* __restrict__ w3,
    const float* __restrict__ b3, float* __restrict__ out,
    unsigned int* __restrict__ flags, unsigned int* __restrict__ ticket) {
  union SmemU {
    struct { _Float16 hist[16][32][72]; _Float16 xs[Tdim][32][8]; } g;  // 136 KB
    struct { _Float16 w1s[32768]; _Float16 rep[8][4][512]; } m;         // 96 KB
  };
  __shared__ __align__(16) SmemU smem;
  __shared__ int s_tk;
  const int tid = threadIdx.x;
  if (tid == 0) s_tk = (int)atomicAdd(ticket, 1u);
  __syncthreads();
  const int tk = s_tk;

  const int lane = tid & 63;
  const int w8 = tid >> 6;                    // wave id 0..7
  const int c = lane & 15;                    // MFMA col
  const int q = lane >> 4;                    // quad

  if (tk < NGRU) {
    // =============================== GRU role (verbatim v2 structure) ====
    const int gb = tk;
    auto& hist = smem.g.hist;
    auto& xs = smem.g.xs;
    const int s = w8 >> 2;                    // stream 0/1
    const int w = w8 & 3;                     // gate-tile wave within stream
    const int s16c = s * 16 + c;

    // ---- preload x for this block's 32 rows, pre-converted to fp16
    for (int i = 0; i < 8; i++) {
      int idx = i * 512 + tid;                // 0..4095 = (t, row)
      int t = idx >> 5, row = idx & 31;
      int nr = gb * 32 + row;                 // n = z*32 + b
      const float* p = x + (size_t)(nr & 31) * (Tdim * Zdim * Sdim)
                         + (size_t)t * (Zdim * Sdim) + (size_t)(nr >> 5) * Sdim;
      f16x8 v;
      v[0] = (_Float16)p[0]; v[1] = (_Float16)p[1]; v[2] = (_Float16)p[2];
      v[3] = (_Float16)p[3]; v[4] = (_Float16)p[4]; v[5] = (_Float16)p[5];
      v[6] = (_Float16)0.f;  v[7] = (_Float16)0.f;
      *(f16x8*)&xs[t][row][0] = v;
    }

    const int gr0 = w * 16;
    const int gz0 = 64 + w * 16;
    const int gn0 = 128 + w * 16;

    f16x8 Ar[3], Az[3], Anh[2], Ani;
#pragma unroll
    for (int kf = 0; kf < 3; kf++) {
      Ar[kf] = *(const f16x8*)(Wf + (size_t)(gr0 + c) * 96 + kf * 32 + q * 8);
      Az[kf] = *(const f16x8*)(Wf + (size_t)(gz0 + c) * 96 + kf * 32 + q * 8);
    }
    Anh[0] = *(const f16x8*)(Wf + (size_t)(gn0 + c) * 96 + q * 8);
    Anh[1] = *(const f16x8*)(Wf + (size_t)(gn0 + c) * 96 + 32 + q * 8);
    Ani    = *(const f16x8*)(Wf + (size_t)(gn0 + c) * 96 + 64 + q * 8);

    f32x4 Cr, Cz, Cnh, Cni;
    {
      f32x4 bir = *(const f32x4*)(b_ih + gr0 + q * 4);
      f32x4 bhr = *(const f32x4*)(b_hh + gr0 + q * 4);
      f32x4 biz = *(const f32x4*)(b_ih + gz0 + q * 4);
      f32x4 bhz = *(const f32x4*)(b_hh + gz0 + q * 4);
#pragma unroll
      for (int r = 0; r < 4; r++) { Cr[r] = bir[r] + bhr[r]; Cz[r] = biz[r] + bhz[r]; }
      Cnh = *(const f32x4*)(b_hh + gn0 + q * 4);
      Cni = *(const f32x4*)(b_ih + gn0 + q * 4);
    }

    const uint32_t xmask = (q == 0) ? 0xffffffffu : 0u;

    __syncthreads();                          // xs ready

    f16x8 Bh0 = {0, 0, 0, 0, 0, 0, 0, 0};
    f16x8 Bh1 = {0, 0, 0, 0, 0, 0, 0, 0};
    f32x4 hprev = {0.f, 0.f, 0.f, 0.f};

    f32x4 Dr_s, Dz_s, Dni_s;
    {
      u32x4 xv = *(const u32x4*)&xs[0][s16c][0];
      xv[0] &= xmask; xv[1] &= xmask; xv[2] &= xmask; xv[3] &= xmask;
      f16x8 Bx = *(f16x8*)&xv;
      Dni_s = __builtin_amdgcn_mfma_f32_16x16x32_f16(Ani, Bx, Cni, 0, 0, 0);
      Dr_s  = __builtin_amdgcn_mfma_f32_16x16x32_f16(Ar[2], Bx, Cr, 0, 0, 0);
      Dz_s  = __builtin_amdgcn_mfma_f32_16x16x32_f16(Az[2], Bx, Cz, 0, 0, 0);
    }

#pragma unroll 1
    for (int tch = 0; tch < 8; tch++) {
#pragma unroll 1
      for (int tc = 0; tc < 16; tc++) {
        const int t = tch * 16 + tc;
        f32x4 Dnh = __builtin_amdgcn_mfma_f32_16x16x32_f16(Anh[0], Bh0, Cnh, 0, 0, 0);
        f32x4 Dr  = __builtin_amdgcn_mfma_f32_16x16x32_f16(Ar[0], Bh0, Dr_s, 0, 0, 0);
        f32x4 Dz  = __builtin_amdgcn_mfma_f32_16x16x32_f16(Az[0], Bh0, Dz_s, 0, 0, 0);
        Dnh = __builtin_amdgcn_mfma_f32_16x16x32_f16(Anh[1], Bh1, Dnh, 0, 0, 0);
        Dr  = __builtin_amdgcn_mfma_f32_16x16x32_f16(Ar[1], Bh1, Dr, 0, 0, 0);
        Dz  = __builtin_amdgcn_mfma_f32_16x16x32_f16(Az[1], Bh1, Dz, 0, 0, 0);

        f16x4 pk;
#pragma unroll
        for (int r = 0; r < 4; r++) {
          float er = __expf(-Dr[r]);
          float rr = fast_rcp(1.f + er);
          float ez = __expf(-Dz[r]);
          float zg = fast_rcp(1.f + ez);
          float na = Dni_s[r] + rr * Dnh[r];
          float en = __expf(2.f * na);
          float nn = 1.f - 2.f * fast_rcp(en + 1.f);
          float hnew = nn + zg * (hprev[r] - nn);
          hprev[r] = hnew;
          pk[r] = (_Float16)hnew;
        }
        *(f16x4*)&hist[tc][s16c][w * 16 + q * 4] = pk;

        if (t + 1 < Tdim) {
          u32x4 xv = *(const u32x4*)&xs[t + 1][s16c][0];
          xv[0] &= xmask; xv[1] &= xmask; xv[2] &= xmask; xv[3] &= xmask;
          f16x8 Bx = *(f16x8*)&xv;
          Dni_s = __builtin_amdgcn_mfma_f32_16x16x32_f16(Ani, Bx, Cni, 0, 0, 0);
          Dr_s  = __builtin_amdgcn_mfma_f32_16x16x32_f16(Ar[2], Bx, Cr, 0, 0, 0);
          Dz_s  = __builtin_amdgcn_mfma_f32_16x16x32_f16(Az[2], Bx, Cz, 0, 0, 0);
        }
        __syncthreads();                      // h exchange across gate waves
        Bh0 = *(const f16x8*)&hist[tc][s16c][q * 8];
        Bh1 = *(const f16x8*)&hist[tc][s16c][32 + q * 8];
      }
      // coalesced dump of the 16-step chunk; wave w8 handles rows 4*w8..+3
      {
        const int t0 = tch * 16;
#pragma unroll
        for (int rr2 = 0; rr2 < 4; rr2++) {
          const int row = w8 * 4 + rr2;
          const int nrow = gb * 32 + row;
          _Float16* dst = sx + (size_t)nrow * Tdim * Hdim + (size_t)t0 * Hdim;
#pragma unroll
          for (int it = 0; it < 2; it++) {
            int idx = it * 64 + lane;         // 0..127
            int tcc = idx >> 3, hd8 = idx & 7;
            f16x8 vv = *(const f16x8*)&hist[tcc][row][hd8 * 8];
            *(f16x8*)(dst + tcc * 64 + hd8 * 8) = vv;
          }
        }
        __syncthreads();                      // dump drained (vmcnt 0) + hist reusable
        if (tid == 0) {
          __threadfence();                    // agent-scope: L2 writeback of sx
          atomicAdd(&flags[gb * 8 + tch], 1u);// publish chunk
        }
      }
    }
  } else {
    // =============================== MLP role ===========================
    const int mid = tk - NGRU;                // 0..799
    const int gbm = mid % NGRU;               // producer gru block
    const int ch  = mid / NGRU;               // chunk 0..7 (early tickets -> early chunks)
    auto& w1s = smem.m.w1s;
    auto& rep = smem.m.rep;

    // ---- stage all of w1 into LDS while waiting (64 KB)
    {
      const u32x4* srcw = (const u32x4*)w1p;  // 4096 u32x4
      u32x4* dstw = (u32x4*)w1s;
#pragma unroll
      for (int i = 0; i < 8; i++)
        dstw[i * 512 + tid] = srcw[i * 512 + tid];
    }
    // ---- wait for producer chunk
    if (tid == 0) {
      while (__hip_atomic_load(&flags[gbm * 8 + ch], __ATOMIC_RELAXED,
                               __HIP_MEMORY_SCOPE_AGENT) == 0u)
        __builtin_amdgcn_s_sleep(2);
      (void)__hip_atomic_load(&flags[gbm * 8 + ch], __ATOMIC_ACQUIRE,
                              __HIP_MEMORY_SCOPE_AGENT);  // inv caches
    }
    __syncthreads();                          // flag seen + w1s ready

    // wave w8 owns 4 seqs x 16 timesteps: row(g,c) = (seqB+g)*128 + ch*16 + c
    const int seqB = gbm * 32 + w8 * 4;
    const size_t tB = (size_t)ch * 16;

    f16x8 Bs[4][2];
#pragma unroll
    for (int g = 0; g < 4; g++)
#pragma unroll
      for (int kk = 0; kk < 2; kk++)
        Bs[g][kk] = *(const f16x8*)(sx + ((size_t)(seqB + g) * Tdim + tB + c) * Hdim
                                    + kk * 32 + q * 8);

    f32x4 acc2[4][8];
#pragma unroll
    for (int g = 0; g < 4; g++)
#pragma unroll
      for (int nt = 0; nt < 8; nt++) acc2[g][nt] = (f32x4){0.f, 0.f, 0.f, 0.f};

    // ---- prologue: layer1 for kt=0 into rep
    {
#pragma unroll
      for (int ntl = 0; ntl < 2; ntl++) {
        f16x8 A0 = *(const f16x8*)&w1s[ntl * 1024 + lane * 8];
        f16x8 A1 = *(const f16x8*)&w1s[ntl * 1024 + 512 + lane * 8];
        f32x4 bb = *(const f32x4*)(b1 + ntl * 16 + q * 4);
        const int roff = ((2 * ntl + (q >> 1)) * 16 + c) * 8 + (q & 1) * 4;
#pragma unroll
        for (int g = 0; g < 4; g++) {
          f32x4 cc = __builtin_amdgcn_mfma_f32_16x16x32_f16(A0, Bs[g][0], bb, 0, 0, 0);
          cc = __builtin_amdgcn_mfma_f32_16x16x32_f16(A1, Bs[g][1], cc, 0, 0, 0);
          f16x4 pk;
#pragma unroll
          for (int r = 0; r < 4; r++)
            pk[r] = (_Float16)(cc[r] > 0.f ? cc[r] : 0.f);
          *(f16x4*)&rep[w8][g][roff] = pk;
        }
      }
    }

#pragma unroll 1
    for (int kt = 0; kt < 16; kt++) {
      const int ktn = kt + 1;
      const bool more = (ktn < 16);
      f16x8 A2[8];                            // layer2 weights for kt (global/L2)
#pragma unroll
      for (int nt = 0; nt < 8; nt++)
        A2[nt] = *(const f16x8*)(w2p + (size_t)kt * 4096 + nt * 512 + lane * 8);
      f16x8 W0[2], W1[2];                     // layer1 weights for kt+1 (LDS)
      f32x4 bb[2];
      {
        const int kts = more ? ktn : kt;
#pragma unroll
        for (int ntl = 0; ntl < 2; ntl++) {
          W0[ntl] = *(const f16x8*)&w1s[kts * 2048 + ntl * 1024 + lane * 8];
          W1[ntl] = *(const f16x8*)&w1s[kts * 2048 + ntl * 1024 + 512 + lane * 8];
          bb[ntl] = *(const f32x4*)(b1 + kts * 32 + ntl * 16 + q * 4);
        }
      }
      f16x8 Ba[4];                            // a1(kt), written last iteration
#pragma unroll
      for (int g = 0; g < 4; g++)
        Ba[g] = *(const f16x8*)&rep[w8][g][lane * 8];

      if (more) {
#pragma unroll
        for (int ntl = 0; ntl < 2; ntl++) {
          const int roff = ((2 * ntl + (q >> 1)) * 16 + c) * 8 + (q & 1) * 4;
#pragma unroll
          for (int g = 0; g < 4; g++) {
            f32x4 cc = __builtin_amdgcn_mfma_f32_16x16x32_f16(W0[ntl], Bs[g][0], bb[ntl], 0, 0, 0);
            cc = __builtin_amdgcn_mfma_f32_16x16x32_f16(W1[ntl], Bs[g][1], cc, 0, 0, 0);
            f16x4 pk;
#pragma unroll
            for (int r = 0; r < 4; r++)
              pk[r] = (_Float16)(cc[r] > 0.f ? cc[r] : 0.f);
            *(f16x4*)&rep[w8][g][roff] = pk;
          }
        }
      }

#pragma unroll
      for (int nt = 0; nt < 8; nt++)
#pragma unroll
        for (int g = 0; g < 4; g++)
          acc2[g][nt] = __builtin_amdgcn_mfma_f32_16x16x32_f16(A2[nt], Ba[g], acc2[g][nt], 0, 0, 0);
    }

    // ---- layer3: out[row] = sum relu(a2 + b2) * w3 + b3
    float part[4] = {0.f, 0.f, 0.f, 0.f};
#pragma unroll
    for (int nt = 0; nt < 8; nt++) {
      f32x4 bb = *(const f32x4*)(b2 + nt * 16 + q * 4);
      f32x4 ww = *(const f32x4*)(w3 + nt * 16 + q * 4);
#pragma unroll
      for (int g = 0; g < 4; g++) {
#pragma unroll
        for (int r = 0; r < 4; r++) {
          float v = acc2[g][nt][r] + bb[r];
          v = v > 0.f ? v : 0.f;
          part[g] = fmaf(v, ww[r], part[g]);
        }
      }
    }
#pragma unroll
    for (int g = 0; g < 4; g++) {
      part[g] += __shfl_xor(part[g], 16, 64);
      part[g] += __shfl_xor(part[g], 32, 64);
    }
    // lane (c,q) writes seq seqB+q, timestep ch*16+c
    float pv = (q == 0) ? part[0] : (q == 1) ? part[1] : (q == 2) ? part[2] : part[3];
    out[(size_t)(seqB + q) * Tdim + tB + c] = pv + b3[0];
  }
}

// ----------------------------------------------------------------
extern "C" void kernel_launch(void* const* d_in, const int* in_sizes, int n_in,
                              void* d_out, int out_size, void* d_ws, size_t ws_size,
                              hipStream_t stream) {
  const float* x    = (const float*)d_in[0];
  const float* W_ih = (const float*)d_in[1];
  const float* W_hh = (const float*)d_in[2];
  const float* b_ih = (const float*)d_in[3];
  const float* b_hh = (const float*)d_in[4];
  const float* w1   = (const float*)d_in[5];
  const float* b1   = (const float*)d_in[6];
  const float* w2   = (const float*)d_in[7];
  const float* b2   = (const float*)d_in[8];
  const float* w3   = (const float*)d_in[9];
  const float* b3   = (const float*)d_in[10];
  float* out = (float*)d_out;

  char* ws = (char*)d_ws;
  _Float16* sxf = (_Float16*)ws;                               // 52,428,800 B
  _Float16* Wf  = (_Float16*)(ws + 52428800);                  // 36,864 B
  _Float16* w1p = (_Float16*)(ws + 52428800 + 36864);          // 65,536 B
  _Float16* w2p = (_Float16*)(ws + 52428800 + 36864 + 65536);  // 131,072 B
  unsigned int* syncb = (unsigned int*)(ws + 52428800 + 36864 + 65536 + 131072); // 3,204 B
  unsigned int* flags  = syncb;        // [800]
  unsigned int* ticket = syncb + 800;  // [1]

  hipLaunchKernelGGL(prep_kernel, dim3(456), dim3(256), 0, stream,
                     W_ih, W_hh, w1, w2, Wf, w1p, w2p, syncb);
  hipLaunchKernelGGL(fused_kernel, dim3(NGRU + NMLP), dim3(512), 0, stream,
                     x, Wf, b_ih, b_hh, sxf, w1p, w2p, b1, b2, w3, b3, out,
                     flags, ticket);
}